// Round 5
// baseline (302.976 us; speedup 1.0000x reference)
//
#include <hip/hip_runtime.h>
#include <hip/hip_bf16.h>
#include <stdint.h>

typedef __attribute__((ext_vector_type(8))) short short8;
typedef __attribute__((ext_vector_type(4))) float f32x4;

#define XPP_BYTES 66355200ull   // 8rh*8cw*2b*15rho*15cwo*18d*64ci*2B
#define XPP_SLACK 65536ull      // staging over-read pad
#define WPP_BYTES 14155776ull   // 64hw*27tap*64co*64ci*2B

__device__ __forceinline__ void gl2lds16(const void* g, void* l) {
    __builtin_amdgcn_global_load_lds(
        (const __attribute__((address_space(1))) unsigned int*)g,
        (__attribute__((address_space(3))) unsigned int*)l, 16, 0, 0);
}

// ---------------- bzero: zero only X''' halo (rho=0 | cwo=0 | d in {0,17}) --
__global__ __launch_bounds__(256)
void bzero(uint4* __restrict__ xpp) {
    const uint4 z = {0u, 0u, 0u, 0u};
    const int total = 935936;
    for (int idx = blockIdx.x * 256 + threadIdx.x; idx < total;
         idx += gridDim.x * 256) {
        int u;
        if (idx < 276480) {
            int slab = idx / 2160, off = idx % 2160;
            u = slab * 32400 + off;
        } else if (idx < 534528) {
            int k = idx - 276480;
            int run = k / 144, off = k % 144;
            int slab = run / 14, rho = run % 14 + 1;
            u = slab * 32400 + rho * 2160 + off;
        } else {
            int k = idx - 534528;
            int run = k / 8, off = k % 8;
            int slab = run / 392, r2 = run % 392;
            int rho = r2 / 28 + 1, r3 = r2 % 28;
            int cwo = r3 / 2 + 1, d = (r3 & 1) * 17;
            u = slab * 32400 + rho * 2160 + cwo * 144 + d * 8 + off;
        }
        xpp[u] = z;
    }
}

// ---------------- T1: X (f32) -> X''' (bf16, space-to-depth, d-innermost) --
__global__ __launch_bounds__(512)
void xform_x(const float* __restrict__ xin, __hip_bfloat16* __restrict__ xpp) {
    extern __shared__ __hip_bfloat16 Xl[];
    const int bid = blockIdx.x;
    const int rho = bid % 14, d = (bid / 14) % 16, b = bid / 224;
    const int tid = threadIdx.x;
    for (int f = tid; f < 64 * 8 * 28; f += 512) {
        int ci = f / 224, rem = f % 224;
        int r = rem / 28, c4 = (rem % 28) * 4;
        const float4 v = *(const float4*)&xin[
            ((((size_t)b * 64 + ci) * 16 + d) * 112 + (rho * 8 + r)) * 112 + c4];
        const float vv[4] = {v.x, v.y, v.z, v.w};
#pragma unroll
        for (int u = 0; u < 4; ++u) {
            int c = c4 + u;
            Xl[(r * 112 + c) * 64 + (ci ^ ((c & 7) << 3))] = __float2bfloat16(vv[u]);
        }
    }
    __syncthreads();
    for (int f = tid; f < 896 * 8; f += 512) {
        int pos = f >> 3, j = f & 7;
        int r = pos / 112, c = pos % 112;
        int cw = c & 7, cwo = c >> 3;
        uint4 v = *(const uint4*)&Xl[pos * 64 + ((j * 8) ^ ((c & 7) << 3))];
        size_t dst = (((((size_t)(r * 8 + cw) * 2 + b) * 15 + (rho + 1)) * 15
                       + (cwo + 1)) * 18 + (d + 1)) * 64 + j * 8;
        *(uint4*)(xpp + dst) = v;
    }
}

// ---------------- T2: W (f32) -> W''[hw][tap][co][ci] (bf16) ---------------
__global__ __launch_bounds__(256)
void xform_w(const float* __restrict__ wt, __hip_bfloat16* __restrict__ wpp) {
    __shared__ __hip_bfloat16 lw[8 * 27 * 72];
    const int hw = blockIdx.x >> 3, cc = blockIdx.x & 7;
    for (int f = threadIdx.x; f < 8 * 64 * 27; f += 256) {
        int k = f % 27, ci = (f / 27) % 64, co = f / (27 * 64);
        float v = wt[(size_t)hw * 110592 + (size_t)(cc * 8 + co) * 1728 + ci * 27 + k];
        lw[(co * 27 + k) * 72 + ci] = __float2bfloat16(v);
    }
    __syncthreads();
    for (int f = threadIdx.x; f < 27 * 8 * 8; f += 256) {
        int cic = f % 8, co = (f / 8) % 8, k = f / 64;
        uint4 v = *(const uint4*)&lw[(co * 27 + k) * 72 + cic * 8];
        size_t dst = (((size_t)hw * 27 + k) * 64 + (cc * 8 + co)) * 64 + cic * 8;
        *(uint4*)(wpp + dst) = v;
    }
}

// ---------------- GEMM: per (h,w,b,mc): [224m x 64co], m=(wo,t) ------------
// 18 half-steps (9 rounds x 2 ci-halves). 4 LDS half-buffers (16 KB each),
// counted vmcnt (even: 8, odd: 20), raw s_barrier — loads 3 halves in flight.
// B one round ahead in regs. Conflict-free 64B-row layout: q' = q^((d>>1)&3).

#define STG(S) do {                                                          \
    const int s3_ = (S);                                                     \
    const int rr_ = s3_ >> 1, kh_ = rr_ / 3, kw_ = rr_ % 3;                  \
    const int r0_ = h + kh_ - 7, c0_ = w + kw_ - 7;                          \
    const char* ap_ = (const char*)xpp +                                     \
        (size_t)(((((r0_ & 7) * 8 + (c0_ & 7)) * 2 + b) * 15                 \
                  + ((r0_ >> 3) + 1 + mc)) * 15 + ((c0_ >> 3) + 1)) * 2304   \
        + (s3_ & 1) * 64;                                                    \
    char* Ad_ = smem + (s3_ & 3) * 16384;                                    \
    _Pragma("unroll")                                                        \
    for (int i_ = 0; i_ < 4; ++i_)                                           \
        gl2lds16(ap_ + srcoff[i_], Ad_ + (uint32_t)(tid + i_ * 256) * 16);   \
} while (0)

#define LDB(R, DST) do {                                                     \
    const char* bp_ = wbase + (size_t)(R) * 8192;                            \
    _Pragma("unroll")                                                        \
    for (int kd_ = 0; kd_ < 3; ++kd_)                                        \
    _Pragma("unroll")                                                        \
    for (int ks_ = 0; ks_ < 2; ++ks_)                                        \
    _Pragma("unroll")                                                        \
    for (int n_ = 0; n_ < 2; ++n_)                                           \
        DST[kd_ * 4 + ks_ * 2 + n_] = *(const short8*)(                      \
            bp_ + kd_ * 73728 + (ng * 2 + n_) * 2048 + ks_ * 64 + bofs);     \
} while (0)

#define WINDOW(S, R, CUR, NXT, KS, DOB, DOA, WAITN) do {                     \
    if ((WAITN) == 0)      asm volatile("s_waitcnt vmcnt(0)" ::: "memory");  \
    else if ((WAITN) == 4) asm volatile("s_waitcnt vmcnt(4)" ::: "memory");  \
    else if ((WAITN) == 8) asm volatile("s_waitcnt vmcnt(8)" ::: "memory");  \
    else                   asm volatile("s_waitcnt vmcnt(20)" ::: "memory"); \
    __builtin_amdgcn_s_barrier();                                            \
    {   const char* Ab_ = smem + ((S) & 3) * 16384;                          \
        _Pragma("unroll")                                                    \
        for (int kd = 0; kd < 3; ++kd) {                                     \
            short8 af_[7];                                                   \
            _Pragma("unroll")                                                \
            for (int j_ = 0; j_ < 7; ++j_)                                   \
                af_[j_] = *(const short8*)(Ab_ + (mg * 7 + j_) * 1152        \
                                           + rofs[kd]);                      \
            if (kd == 0) {                                                   \
                __builtin_amdgcn_sched_barrier(0);                           \
                if (DOB) LDB((R) + 1, NXT);                                  \
                if (DOA) STG((S) + 3);                                       \
                __builtin_amdgcn_sched_barrier(0);                           \
            }                                                                \
            __builtin_amdgcn_s_setprio(1);                                   \
            _Pragma("unroll")                                                \
            for (int j_ = 0; j_ < 7; ++j_)                                   \
                _Pragma("unroll")                                            \
                for (int n_ = 0; n_ < 2; ++n_)                               \
                    acc[j_][n_] = __builtin_amdgcn_mfma_f32_16x16x32_bf16(   \
                        af_[j_], CUR[kd * 4 + (KS) * 2 + n_],                \
                        acc[j_][n_], 0, 0, 0);                               \
            __builtin_amdgcn_s_setprio(0);                                   \
        } }                                                                  \
} while (0)

__global__ __launch_bounds__(256, 2)
void patgemm(const __hip_bfloat16* __restrict__ xpp,
             const __hip_bfloat16* __restrict__ wpp,
             const float* __restrict__ bs,
             float* __restrict__ out) {
    extern __shared__ char smem[];  // 4 x 16384 B ci-half buffers
    const int bid = blockIdx.x;
    const int h = bid & 7, k = bid >> 3;
    const int w = k & 7, b = (k >> 3) & 1, mc = k >> 4;
    const int hw = h * 8 + w;
    const int tid = threadIdx.x, wv = tid >> 6, lane = tid & 63;
    const int col = lane & 15, quad = lane >> 4;
    const int mg = wv >> 1, ng = wv & 1;

    // staging source offsets: slot u -> (wo, d, q'); source chunk q = q'^((d>>1)&3)
    uint32_t srcoff[4];
#pragma unroll
    for (int i = 0; i < 4; ++i) {
        int u = tid + i * 256; if (u > 1007) u = 1007;
        int wo = u / 72, rem = u % 72;
        int d = rem >> 2, qp = rem & 3, q = qp ^ ((d >> 1) & 3);
        srcoff[i] = (uint32_t)(wo * 2304 + d * 128 + q * 16);
    }
    // fragment read offsets per kd (row = col+kd, swizzled chunk)
    uint32_t rofs[3];
#pragma unroll
    for (int kd = 0; kd < 3; ++kd)
        rofs[kd] = (uint32_t)((col + kd) * 64
            + ((quad ^ (((col + kd) >> 1) & 3)) << 4));
    const uint32_t bofs = (uint32_t)(col * 128 + quad * 16);

    f32x4 acc[7][2];
#pragma unroll
    for (int j = 0; j < 7; ++j)
#pragma unroll
        for (int n = 0; n < 2; ++n) acc[j][n] = (f32x4){0.f, 0.f, 0.f, 0.f};

    const char* wbase = (const char*)wpp + (size_t)hw * 27 * 8192;
    short8 bfrA[12], bfrB[12];

    // prologue — FIFO: [A0, B0, A1, A2]
    STG(0);
    __builtin_amdgcn_sched_barrier(0);
    LDB(0, bfrA);
    __builtin_amdgcn_sched_barrier(0);
    STG(1);
    STG(2);

#pragma unroll 1
    for (int rp = 0; rp < 4; ++rp) {
        const int ra = 2 * rp, rb = 2 * rp + 1;
        WINDOW(2 * ra,     ra, bfrA, bfrB, 0, 1, 1, 8);
        WINDOW(2 * ra + 1, ra, bfrA, bfrB, 1, 0, 1, 20);
        WINDOW(2 * rb,     rb, bfrB, bfrA, 0, 1, 1, 8);
        WINDOW(2 * rb + 1, rb, bfrB, bfrA, 1, 0, (rb < 7), 20);
    }
    WINDOW(16, 8, bfrA, bfrB, 0, 0, 0, 4);
    WINDOW(17, 8, bfrA, bfrB, 1, 0, 0, 0);

    // epilogue: D col=lane&15 (co-within-tile / t source), row=quad*4+jj (t)
    const float* bsl = bs + hw * 64;
    const int y = 8 * mc + h;
#pragma unroll
    for (int j = 0; j < 7; ++j) {
        const int wo = mg * 7 + j;
        const int x = 8 * wo + w;
#pragma unroll
        for (int n = 0; n < 2; ++n) {
            const int co = (ng * 2 + n) * 16 + col;
            const float bv = bsl[co];
#pragma unroll
            for (int jj = 0; jj < 4; ++jj) {
                const int t = quad * 4 + jj;
                out[((((size_t)b * 64 + co) * 16 + t) * 112 + y) * 112 + x]
                    = acc[j][n][jj] + bv;
            }
        }
    }
}

// ---------------- fallback: round-1 fp32 kernel (used if ws too small) -----
#define XL_ROWSTRIDE 116
#define WL_WSTRIDE (17*27)

__global__ __launch_bounds__(256, 3)
void patconv3d_fp32(const float* __restrict__ xin,
                    const float* __restrict__ wt,
                    const float* __restrict__ bs,
                    float* __restrict__ out) {
    __shared__ float Xl[3*3*7*XL_ROWSTRIDE];
    __shared__ float Wl[8*WL_WSTRIDE];
    const int bid = blockIdx.x;
    const int ct = bid & 3, hb = (bid >> 2) & 1, h = (bid >> 3) & 7;
    const int t = (bid >> 6) & 15, b = (bid >> 10) & 1;
    const int tid = threadIdx.x;
    const int xl = tid & 127, cg = tid >> 7;
    const int xr = (xl < 112) ? xl : 111;
    const int wq = xl & 7;
    float acc[8][7];
#pragma unroll
    for (int c = 0; c < 8; ++c)
#pragma unroll
        for (int ho = 0; ho < 7; ++ho) acc[c][ho] = 0.f;
    for (int ci = 0; ci < 64; ++ci) {
        __syncthreads();
        for (int idx = tid; idx < 3 * 3 * 7 * 114; idx += 256) {
            int c = idx % 114, rest = idx / 114;
            int ho = rest % 7; rest /= 7;
            int kh = rest % 3, kd = rest / 3;
            int r = 8 * (hb * 7 + ho) + h + kh - 7;
            int d = t + kd - 1, colx = c - 7;
            float v = 0.f;
            if (r >= 0 && d >= 0 && d < 16 && colx >= 0)
                v = xin[(((size_t)(b * 64 + ci) * 16 + d) * 112 + r) * 112 + colx];
            Xl[((kd * 3 + kh) * 7 + ho) * XL_ROWSTRIDE + c] = v;
        }
        for (int idx = tid; idx < 8 * 16 * 27; idx += 256) {
            int k2 = idx % 27, rest = idx / 27;
            int co_l = rest % 16, wi = rest / 16;
            Wl[wi * WL_WSTRIDE + co_l * 27 + k2] =
                wt[(((size_t)(h * 8 + wi) * 64 + (ct * 16 + co_l)) * 64 + ci) * 27 + k2];
        }
        __syncthreads();
#pragma unroll
        for (int kd = 0; kd < 3; ++kd)
#pragma unroll
            for (int kh = 0; kh < 3; ++kh)
#pragma unroll
                for (int kw = 0; kw < 3; ++kw) {
                    const int k2 = (kd * 3 + kh) * 3 + kw;
                    float xv[7];
#pragma unroll
                    for (int ho = 0; ho < 7; ++ho)
                        xv[ho] = Xl[((kd * 3 + kh) * 7 + ho) * XL_ROWSTRIDE + xr + kw];
                    float wv[8];
#pragma unroll
                    for (int c = 0; c < 8; ++c)
                        wv[c] = Wl[wq * WL_WSTRIDE + (cg * 8 + c) * 27 + k2];
#pragma unroll
                    for (int c = 0; c < 8; ++c)
#pragma unroll
                        for (int ho = 0; ho < 7; ++ho)
                            acc[c][ho] += wv[c] * xv[ho];
                }
    }
    if (xl < 112) {
#pragma unroll
        for (int c = 0; c < 8; ++c) {
            const int co = ct * 16 + cg * 8 + c;
            const float bv = bs[(h * 8 + wq) * 64 + co];
#pragma unroll
            for (int ho = 0; ho < 7; ++ho) {
                const int y = 8 * (hb * 7 + ho) + h;
                out[(((size_t)(b * 64 + co) * 16 + t) * 112 + y) * 112 + xl] = acc[c][ho] + bv;
            }
        }
    }
}

extern "C" void kernel_launch(void* const* d_in, const int* in_sizes, int n_in,
                              void* d_out, int out_size, void* d_ws, size_t ws_size,
                              hipStream_t stream) {
    const float* x  = (const float*)d_in[0];
    const float* wg = (const float*)d_in[1];
    const float* bi = (const float*)d_in[2];
    float* out = (float*)d_out;
    if (ws_size >= XPP_BYTES + XPP_SLACK + WPP_BYTES) {
        __hip_bfloat16* xpp = (__hip_bfloat16*)d_ws;
        __hip_bfloat16* wpp = (__hip_bfloat16*)((char*)d_ws + XPP_BYTES + XPP_SLACK);
        bzero<<<1024, 256, 0, stream>>>((uint4*)d_ws);
        xform_x<<<448, 512, 114688, stream>>>(x, xpp);
        xform_w<<<512, 256, 0, stream>>>(wg, wpp);
        patgemm<<<1792, 256, 65536, stream>>>(xpp, wpp, bi, out);
    } else {
        patconv3d_fp32<<<2048, 256, 0, stream>>>(x, wg, bi, out);
    }
}

// Round 6
// 297.994 us; speedup vs baseline: 1.0167x; 1.0167x over previous
//
#include <hip/hip_runtime.h>
#include <hip/hip_bf16.h>
#include <stdint.h>

typedef __attribute__((ext_vector_type(8))) short short8;
typedef __attribute__((ext_vector_type(4))) float f32x4;

#define XPP_BYTES 66355200ull   // 8rh*8cw*2b*15rho*15cwo*18d*64ci*2B
#define XPP_SLACK 65536ull      // staging over-read pad
#define WPP_BYTES 14155776ull   // 64hw*27tap*64co*64ci*2B

__device__ __forceinline__ void gl2lds16(const void* g, void* l) {
    __builtin_amdgcn_global_load_lds(
        (const __attribute__((address_space(1))) unsigned int*)g,
        (__attribute__((address_space(3))) unsigned int*)l, 16, 0, 0);
}

// ---------------- bzero: zero only X''' halo (rho=0 | cwo=0 | d in {0,17}) --
__global__ __launch_bounds__(256)
void bzero(uint4* __restrict__ xpp) {
    const uint4 z = {0u, 0u, 0u, 0u};
    const int total = 935936;
    for (int idx = blockIdx.x * 256 + threadIdx.x; idx < total;
         idx += gridDim.x * 256) {
        int u;
        if (idx < 276480) {
            int slab = idx / 2160, off = idx % 2160;
            u = slab * 32400 + off;
        } else if (idx < 534528) {
            int k = idx - 276480;
            int run = k / 144, off = k % 144;
            int slab = run / 14, rho = run % 14 + 1;
            u = slab * 32400 + rho * 2160 + off;
        } else {
            int k = idx - 534528;
            int run = k / 8, off = k % 8;
            int slab = run / 392, r2 = run % 392;
            int rho = r2 / 28 + 1, r3 = r2 % 28;
            int cwo = r3 / 2 + 1, d = (r3 & 1) * 17;
            u = slab * 32400 + rho * 2160 + cwo * 144 + d * 8 + off;
        }
        xpp[u] = z;
    }
}

// ---------------- T1: X (f32) -> X''' (bf16, space-to-depth, d-innermost) --
__global__ __launch_bounds__(512)
void xform_x(const float* __restrict__ xin, __hip_bfloat16* __restrict__ xpp) {
    extern __shared__ __hip_bfloat16 Xl[];
    const int bid = blockIdx.x;
    const int rho = bid % 14, d = (bid / 14) % 16, b = bid / 224;
    const int tid = threadIdx.x;
    for (int f = tid; f < 64 * 8 * 28; f += 512) {
        int ci = f / 224, rem = f % 224;
        int r = rem / 28, c4 = (rem % 28) * 4;
        const float4 v = *(const float4*)&xin[
            ((((size_t)b * 64 + ci) * 16 + d) * 112 + (rho * 8 + r)) * 112 + c4];
        const float vv[4] = {v.x, v.y, v.z, v.w};
#pragma unroll
        for (int u = 0; u < 4; ++u) {
            int c = c4 + u;
            Xl[(r * 112 + c) * 64 + (ci ^ ((c & 7) << 3))] = __float2bfloat16(vv[u]);
        }
    }
    __syncthreads();
    for (int f = tid; f < 896 * 8; f += 512) {
        int pos = f >> 3, j = f & 7;
        int r = pos / 112, c = pos % 112;
        int cw = c & 7, cwo = c >> 3;
        uint4 v = *(const uint4*)&Xl[pos * 64 + ((j * 8) ^ ((c & 7) << 3))];
        size_t dst = (((((size_t)(r * 8 + cw) * 2 + b) * 15 + (rho + 1)) * 15
                       + (cwo + 1)) * 18 + (d + 1)) * 64 + j * 8;
        *(uint4*)(xpp + dst) = v;
    }
}

// ---------------- T2: W (f32) -> W''[hw][tap][co][ci] (bf16) ---------------
__global__ __launch_bounds__(256)
void xform_w(const float* __restrict__ wt, __hip_bfloat16* __restrict__ wpp) {
    __shared__ __hip_bfloat16 lw[8 * 27 * 72];
    const int hw = blockIdx.x >> 3, cc = blockIdx.x & 7;
    for (int f = threadIdx.x; f < 8 * 64 * 27; f += 256) {
        int k = f % 27, ci = (f / 27) % 64, co = f / (27 * 64);
        float v = wt[(size_t)hw * 110592 + (size_t)(cc * 8 + co) * 1728 + ci * 27 + k];
        lw[(co * 27 + k) * 72 + ci] = __float2bfloat16(v);
    }
    __syncthreads();
    for (int f = threadIdx.x; f < 27 * 8 * 8; f += 256) {
        int cic = f % 8, co = (f / 8) % 8, k = f / 64;
        uint4 v = *(const uint4*)&lw[(co * 27 + k) * 72 + cic * 8];
        size_t dst = (((size_t)hw * 27 + k) * 64 + (cc * 8 + co)) * 64 + cic * 8;
        *(uint4*)(wpp + dst) = v;
    }
}

// ---------------- GEMM: per (h,w,b,mc): [224m x 64co], m=(wo,t) ------------
// 512 threads = 8 waves (mg 2 x ng 4); each wave 7 m-tiles x 1 n-tile.
// 18 windows (9 (kh,kw)-rounds x 2 ci-halves); 4 x 16 KB LDS ring; counted
// vmcnt (w0:4, w1-15:2, w16-17:0); B per-window in regs (2 slots).

#define STG(S) do {                                                          \
    const int s3_ = (S);                                                     \
    const int rr_ = s3_ >> 1, kh_ = rr_ / 3, kw_ = rr_ % 3;                  \
    const int r0_ = h + kh_ - 7, c0_ = w + kw_ - 7;                          \
    const char* ap_ = (const char*)xpp +                                     \
        (size_t)(((((r0_ & 7) * 8 + (c0_ & 7)) * 2 + b) * 15                 \
                  + ((r0_ >> 3) + 1 + mc)) * 15 + ((c0_ >> 3) + 1)) * 2304   \
        + (s3_ & 1) * 64;                                                    \
    char* Ad_ = smem + (s3_ & 3) * 16384;                                    \
    _Pragma("unroll")                                                        \
    for (int i_ = 0; i_ < 2; ++i_)                                           \
        gl2lds16(ap_ + srcoff[i_], Ad_ + (uint32_t)(tid + i_ * 512) * 16);   \
} while (0)

#define LDB(S, DST) do {                                                     \
    const int sb_ = (S);                                                     \
    const char* bp_ = wbase + (size_t)(sb_ >> 1) * 8192 + (sb_ & 1) * 64;    \
    _Pragma("unroll")                                                        \
    for (int kd_ = 0; kd_ < 3; ++kd_)                                        \
        DST[kd_] = *(const short8*)(bp_ + kd_ * 73728 + ng * 2048 + bofs);   \
} while (0)

#define WINDOW(S, CUR, NXT, DOB, DOA, WAITN) do {                            \
    if ((WAITN) == 0)      asm volatile("s_waitcnt vmcnt(0)" ::: "memory");  \
    else if ((WAITN) == 4) asm volatile("s_waitcnt vmcnt(4)" ::: "memory");  \
    else                   asm volatile("s_waitcnt vmcnt(2)" ::: "memory");  \
    __builtin_amdgcn_s_barrier();                                            \
    {   const char* Ab_ = smem + ((S) & 3) * 16384;                          \
        _Pragma("unroll")                                                    \
        for (int kd = 0; kd < 3; ++kd) {                                     \
            short8 af_[7];                                                   \
            _Pragma("unroll")                                                \
            for (int j_ = 0; j_ < 7; ++j_)                                   \
                af_[j_] = *(const short8*)(Ab_ + (mg * 7 + j_) * 1152        \
                                           + rofs[kd]);                      \
            if (kd == 0) {                                                   \
                __builtin_amdgcn_sched_barrier(0);                           \
                if (DOB) LDB((S) + 1, NXT);                                  \
                __builtin_amdgcn_sched_barrier(0);                           \
                if (DOA) STG((S) + 3);                                       \
                __builtin_amdgcn_sched_barrier(0);                           \
            }                                                                \
            __builtin_amdgcn_s_setprio(1);                                   \
            _Pragma("unroll")                                                \
            for (int j_ = 0; j_ < 7; ++j_)                                   \
                acc[j_] = __builtin_amdgcn_mfma_f32_16x16x32_bf16(           \
                    af_[j_], CUR[kd], acc[j_], 0, 0, 0);                     \
            __builtin_amdgcn_s_setprio(0);                                   \
        } }                                                                  \
} while (0)

__global__ __launch_bounds__(512, 4)
void patgemm(const __hip_bfloat16* __restrict__ xpp,
             const __hip_bfloat16* __restrict__ wpp,
             const float* __restrict__ bs,
             float* __restrict__ out) {
    extern __shared__ char smem[];  // 4 x 16384 B ci-half buffers
    const int bid = blockIdx.x;
    const int h = bid & 7, k = bid >> 3;
    const int w = k & 7, b = (k >> 3) & 1, mc = k >> 4;
    const int hw = h * 8 + w;
    const int tid = threadIdx.x, wv = tid >> 6, lane = tid & 63;
    const int col = lane & 15, quad = lane >> 4;
    const int mg = wv >> 2, ng = wv & 3;

    // staging source offsets: slot u -> (wo, d, q'); src chunk q = q'^((d>>1)&3)
    uint32_t srcoff[2];
#pragma unroll
    for (int i = 0; i < 2; ++i) {
        int u = tid + i * 512; if (u > 1007) u = 1007;
        int wo = u / 72, rem = u % 72;
        int d = rem >> 2, qp = rem & 3, q = qp ^ ((d >> 1) & 3);
        srcoff[i] = (uint32_t)(wo * 2304 + d * 128 + q * 16);
    }
    // fragment read offsets per kd (row = col+kd, swizzled chunk)
    uint32_t rofs[3];
#pragma unroll
    for (int kd = 0; kd < 3; ++kd)
        rofs[kd] = (uint32_t)((col + kd) * 64
            + ((quad ^ (((col + kd) >> 1) & 3)) << 4));
    const uint32_t bofs = (uint32_t)(col * 128 + quad * 16);

    f32x4 acc[7];
#pragma unroll
    for (int j = 0; j < 7; ++j) acc[j] = (f32x4){0.f, 0.f, 0.f, 0.f};

    const char* wbase = (const char*)wpp + (size_t)hw * 27 * 8192;
    short8 bfrA[3], bfrB[3];

    // prologue — FIFO: [S0(2), B0(3), S1(2), S2(2)]
    STG(0);
    __builtin_amdgcn_sched_barrier(0);
    LDB(0, bfrA);
    __builtin_amdgcn_sched_barrier(0);
    STG(1);
    STG(2);

    WINDOW(0, bfrA, bfrB, 1, 1, 4);
#pragma unroll 1
    for (int kp = 0; kp < 7; ++kp) {
        const int s1 = 2 * kp + 1;
        WINDOW(s1,     bfrB, bfrA, 1, 1, 2);
        WINDOW(s1 + 1, bfrA, bfrB, 1, 1, 2);
    }
    WINDOW(15, bfrB, bfrA, 1, 0, 2);
    WINDOW(16, bfrA, bfrB, 1, 0, 0);
    WINDOW(17, bfrB, bfrA, 0, 0, 0);

    // epilogue: D col=lane&15 (co-within-tile), row=quad*4+jj (t)
    const float* bsl = bs + hw * 64;
    const int y = 8 * mc + h;
    const int co = ng * 16 + col;
    const float bv = bsl[co];
#pragma unroll
    for (int j = 0; j < 7; ++j) {
        const int wo = mg * 7 + j;
        const int x = 8 * wo + w;
#pragma unroll
        for (int jj = 0; jj < 4; ++jj) {
            const int t = quad * 4 + jj;
            out[((((size_t)b * 64 + co) * 16 + t) * 112 + y) * 112 + x]
                = acc[j][jj] + bv;
        }
    }
}

// ---------------- fallback: round-1 fp32 kernel (used if ws too small) -----
#define XL_ROWSTRIDE 116
#define WL_WSTRIDE (17*27)

__global__ __launch_bounds__(256, 3)
void patconv3d_fp32(const float* __restrict__ xin,
                    const float* __restrict__ wt,
                    const float* __restrict__ bs,
                    float* __restrict__ out) {
    __shared__ float Xl[3*3*7*XL_ROWSTRIDE];
    __shared__ float Wl[8*WL_WSTRIDE];
    const int bid = blockIdx.x;
    const int ct = bid & 3, hb = (bid >> 2) & 1, h = (bid >> 3) & 7;
    const int t = (bid >> 6) & 15, b = (bid >> 10) & 1;
    const int tid = threadIdx.x;
    const int xl = tid & 127, cg = tid >> 7;
    const int xr = (xl < 112) ? xl : 111;
    const int wq = xl & 7;
    float acc[8][7];
#pragma unroll
    for (int c = 0; c < 8; ++c)
#pragma unroll
        for (int ho = 0; ho < 7; ++ho) acc[c][ho] = 0.f;
    for (int ci = 0; ci < 64; ++ci) {
        __syncthreads();
        for (int idx = tid; idx < 3 * 3 * 7 * 114; idx += 256) {
            int c = idx % 114, rest = idx / 114;
            int ho = rest % 7; rest /= 7;
            int kh = rest % 3, kd = rest / 3;
            int r = 8 * (hb * 7 + ho) + h + kh - 7;
            int d = t + kd - 1, colx = c - 7;
            float v = 0.f;
            if (r >= 0 && d >= 0 && d < 16 && colx >= 0)
                v = xin[(((size_t)(b * 64 + ci) * 16 + d) * 112 + r) * 112 + colx];
            Xl[((kd * 3 + kh) * 7 + ho) * XL_ROWSTRIDE + c] = v;
        }
        for (int idx = tid; idx < 8 * 16 * 27; idx += 256) {
            int k2 = idx % 27, rest = idx / 27;
            int co_l = rest % 16, wi = rest / 16;
            Wl[wi * WL_WSTRIDE + co_l * 27 + k2] =
                wt[(((size_t)(h * 8 + wi) * 64 + (ct * 16 + co_l)) * 64 + ci) * 27 + k2];
        }
        __syncthreads();
#pragma unroll
        for (int kd = 0; kd < 3; ++kd)
#pragma unroll
            for (int kh = 0; kh < 3; ++kh)
#pragma unroll
                for (int kw = 0; kw < 3; ++kw) {
                    const int k2 = (kd * 3 + kh) * 3 + kw;
                    float xv[7];
#pragma unroll
                    for (int ho = 0; ho < 7; ++ho)
                        xv[ho] = Xl[((kd * 3 + kh) * 7 + ho) * XL_ROWSTRIDE + xr + kw];
                    float wv[8];
#pragma unroll
                    for (int c = 0; c < 8; ++c)
                        wv[c] = Wl[wq * WL_WSTRIDE + (cg * 8 + c) * 27 + k2];
#pragma unroll
                    for (int c = 0; c < 8; ++c)
#pragma unroll
                        for (int ho = 0; ho < 7; ++ho)
                            acc[c][ho] += wv[c] * xv[ho];
                }
    }
    if (xl < 112) {
#pragma unroll
        for (int c = 0; c < 8; ++c) {
            const int co = ct * 16 + cg * 8 + c;
            const float bv = bs[(h * 8 + wq) * 64 + co];
#pragma unroll
            for (int ho = 0; ho < 7; ++ho) {
                const int y = 8 * (hb * 7 + ho) + h;
                out[(((size_t)(b * 64 + co) * 16 + t) * 112 + y) * 112 + xl] = acc[c][ho] + bv;
            }
        }
    }
}

extern "C" void kernel_launch(void* const* d_in, const int* in_sizes, int n_in,
                              void* d_out, int out_size, void* d_ws, size_t ws_size,
                              hipStream_t stream) {
    const float* x  = (const float*)d_in[0];
    const float* wg = (const float*)d_in[1];
    const float* bi = (const float*)d_in[2];
    float* out = (float*)d_out;
    if (ws_size >= XPP_BYTES + XPP_SLACK + WPP_BYTES) {
        __hip_bfloat16* xpp = (__hip_bfloat16*)d_ws;
        __hip_bfloat16* wpp = (__hip_bfloat16*)((char*)d_ws + XPP_BYTES + XPP_SLACK);
        bzero<<<1024, 256, 0, stream>>>((uint4*)d_ws);
        xform_x<<<448, 512, 114688, stream>>>(x, xpp);
        xform_w<<<512, 256, 0, stream>>>(wg, wpp);
        patgemm<<<1792, 512, 65536, stream>>>(xpp, wpp, bi, out);
    } else {
        patconv3d_fp32<<<2048, 256, 0, stream>>>(x, wg, bi, out);
    }
}